// Round 1
// baseline (585.628 us; speedup 1.0000x reference)
//
#include <hip/hip_runtime.h>
#include <hip/hip_bf16.h>

typedef __hip_bfloat16 bf16;
typedef __attribute__((ext_vector_type(8))) short short8;
typedef __attribute__((ext_vector_type(4))) float f32x4;

struct alignas(8) bh4 { bf16 x, y, z, w; };

static __device__ __forceinline__ float b2f(bf16 h) { return __bfloat162float(h); }

// ---------------- fp32 -> bf16 conversion (n multiple of 4) ----------------
__global__ __launch_bounds__(256) void f2b_kernel(const float* __restrict__ s,
                                                  bf16* __restrict__ d, long n) {
  long i = ((long)blockIdx.x * 256 + threadIdx.x) * 4;
  if (i >= n) return;
  float4 v = *(const float4*)(s + i);
  bh4 o;
  o.x = __float2bfloat16(v.x); o.y = __float2bfloat16(v.y);
  o.z = __float2bfloat16(v.z); o.w = __float2bfloat16(v.w);
  *(bh4*)(d + i) = o;
}

// ---------------- bf16 GEMM, C[M,N] = A[M,K] @ W[N,K]^T (+ epilogue) -------
// EPI 0: out bf16 = acc + bias[col]
// EPI 1: out bf16 = tanh(acc + bias[col]); rows >= halfM use W+1024*K, bias+1024,
//        and A shifted so A-row r maps to KVQ query columns.
// EPI 2: out f32 = acc + bias[col] + resid[row*ldc+col]
#define TILE 128
#define BK 64

template <int EPI>
__global__ __launch_bounds__(256)
void gemm_bt(const bf16* __restrict__ A, long lda,
             const bf16* __restrict__ W, int K,
             const float* __restrict__ bias,
             void* __restrict__ Out, long ldc,
             const float* __restrict__ resid,
             int halfM) {
  __shared__ bf16 sA[TILE * BK];
  __shared__ bf16 sB[TILE * BK];

  const int tid = threadIdx.x;
  const long row0 = (long)blockIdx.y * TILE;
  const long col0 = (long)blockIdx.x * TILE;

  if (EPI == 1 && row0 >= halfM) {
    A += 2048L - (long)halfM * lda;   // query half lives at KVQ cols 2048..3071
    W += (long)1024 * K;
    bias += 1024;
  }

  const int wave = tid >> 6;
  const int lane = tid & 63;
  const int wm = wave >> 1, wn = wave & 1;
  const int fr = lane & 15, quad = lane >> 4;

  f32x4 acc[4][4];
#pragma unroll
  for (int i = 0; i < 4; ++i)
#pragma unroll
    for (int j = 0; j < 4; ++j) acc[i][j] = (f32x4)0.0f;

  const int urow = tid >> 3;        // + r*32 per staging round
  const int ucol = (tid & 7) * 8;

  for (int k0 = 0; k0 < K; k0 += BK) {
#pragma unroll
    for (int r = 0; r < 4; ++r) {
      const int rr = r * 32 + urow;
      const bf16* ga = A + (row0 + rr) * lda + k0 + ucol;
      const bf16* gb = W + (col0 + rr) * (long)K + k0 + ucol;
      bf16* la = &sA[(r * 256 + (wave << 6)) * 8];
      bf16* lb = &sB[(r * 256 + (wave << 6)) * 8];
      __builtin_amdgcn_global_load_lds((const __attribute__((address_space(1))) void*)ga,
                                       (__attribute__((address_space(3))) void*)la, 16, 0, 0);
      __builtin_amdgcn_global_load_lds((const __attribute__((address_space(1))) void*)gb,
                                       (__attribute__((address_space(3))) void*)lb, 16, 0, 0);
    }
    __syncthreads();

#pragma unroll
    for (int kk = 0; kk < BK; kk += 32) {
      short8 af[4], bfv[4];
#pragma unroll
      for (int i = 0; i < 4; ++i)
        af[i] = *(const short8*)&sA[(wm * 64 + i * 16 + fr) * BK + kk + quad * 8];
#pragma unroll
      for (int j = 0; j < 4; ++j)
        bfv[j] = *(const short8*)&sB[(wn * 64 + j * 16 + fr) * BK + kk + quad * 8];
#pragma unroll
      for (int i = 0; i < 4; ++i)
#pragma unroll
        for (int j = 0; j < 4; ++j)
          acc[i][j] = __builtin_amdgcn_mfma_f32_16x16x32_bf16(af[i], bfv[j], acc[i][j], 0, 0, 0);
    }
    __syncthreads();
  }

  // epilogue: C/D layout col = lane&15, row = quad*4 + reg  (m89/m91 verified)
#pragma unroll
  for (int i = 0; i < 4; ++i) {
    const long rb = row0 + wm * 64 + i * 16 + quad * 4;
#pragma unroll
    for (int j = 0; j < 4; ++j) {
      const int col = (int)col0 + wn * 64 + j * 16 + fr;
      const float bc = bias[col];
#pragma unroll
      for (int reg = 0; reg < 4; ++reg) {
        const long r = rb + reg;
        float v = acc[i][j][reg] + bc;
        if (EPI == 0) {
          ((bf16*)Out)[r * ldc + col] = __float2bfloat16(v);
        } else if (EPI == 1) {
          ((bf16*)Out)[r * ldc + col] = __float2bfloat16(tanhf(v));
        } else {
          ((float*)Out)[r * ldc + col] = v + resid[r * ldc + col];
        }
      }
    }
  }
}

// ---------------- chunk-64 cumsum + retrieve + LayerNorm -------------------
// grid = 256 blocks (one per (b, chunk)); block = 256 threads x 4 features.
__global__ __launch_bounds__(256)
void scan_ln_kernel(const bf16* __restrict__ KVQ,   // [16384,3072], V at col 1024
                    const bf16* __restrict__ T,     // [32768,1024] tanh values
                    const float* __restrict__ phase_scale,
                    const float* __restrict__ ln_g,
                    const float* __restrict__ ln_b,
                    bf16* __restrict__ out) {
  const int tid = threadIdx.x;
  const long t0 = (long)blockIdx.x * 64;
  const int d = tid * 4;

  const float inv2pi = 0.15915494309189535f;
  float4 ps = *(const float4*)(phase_scale + d);
  float psr[4] = {ps.x * inv2pi, ps.y * inv2pi, ps.z * inv2pi, ps.w * inv2pi};
  float4 g4 = *(const float4*)(ln_g + d);
  float4 b4 = *(const float4*)(ln_b + d);
  float gv[4] = {g4.x, g4.y, g4.z, g4.w};
  float bv[4] = {b4.x, b4.y, b4.z, b4.w};

  float ar[4] = {0.f, 0.f, 0.f, 0.f}, ai[4] = {0.f, 0.f, 0.f, 0.f};
  __shared__ float red[2][4];

  for (int s = 0; s < 64; ++s) {
    const long t = t0 + s;
    bh4 v4 = *(const bh4*)(KVQ + t * 3072 + 1024 + d);
    bh4 tk4 = *(const bh4*)(T + t * 1024 + d);
    bh4 tq4 = *(const bh4*)(T + (t + 16384) * 1024 + d);
    float vv[4] = {b2f(v4.x), b2f(v4.y), b2f(v4.z), b2f(v4.w)};
    float tk[4] = {b2f(tk4.x), b2f(tk4.y), b2f(tk4.z), b2f(tk4.w)};
    float tq[4] = {b2f(tq4.x), b2f(tq4.y), b2f(tq4.z), b2f(tq4.w)};
    float ret[4];
    float lsum = 0.f, lsq = 0.f;
#pragma unroll
    for (int j = 0; j < 4; ++j) {
      float rk = tk[j] * psr[j];   // revolutions: phase/(2*pi)
      float rq = tq[j] * psr[j];
      float ck = __builtin_amdgcn_cosf(rk);
      float sk = __builtin_amdgcn_sinf(rk);
      float cq = __builtin_amdgcn_cosf(rq);
      float sq = __builtin_amdgcn_sinf(rq);
      ar[j] += vv[j] * ck;
      ai[j] += vv[j] * sk;
      ret[j] = (ar[j] * cq + ai[j] * sq) * 0.03125f;  // / sqrt(1024)
      lsum += ret[j];
      lsq += ret[j] * ret[j];
    }
#pragma unroll
    for (int off = 32; off > 0; off >>= 1) {
      lsum += __shfl_down(lsum, off, 64);
      lsq += __shfl_down(lsq, off, 64);
    }
    __syncthreads();
    if ((tid & 63) == 0) { red[0][tid >> 6] = lsum; red[1][tid >> 6] = lsq; }
    __syncthreads();
    float sum = red[0][0] + red[0][1] + red[0][2] + red[0][3];
    float sq2 = red[1][0] + red[1][1] + red[1][2] + red[1][3];
    float mu = sum * (1.0f / 1024.0f);
    float var = sq2 * (1.0f / 1024.0f) - mu * mu;
    float rstd = rsqrtf(var + 1e-5f);
    bh4 o;
    o.x = __float2bfloat16((ret[0] - mu) * rstd * gv[0] + bv[0]);
    o.y = __float2bfloat16((ret[1] - mu) * rstd * gv[1] + bv[1]);
    o.z = __float2bfloat16((ret[2] - mu) * rstd * gv[2] + bv[2]);
    o.w = __float2bfloat16((ret[3] - mu) * rstd * gv[3] + bv[3]);
    *(bh4*)(out + t * 1024 + d) = o;
  }
}

// ---------------------------------------------------------------------------
extern "C" void kernel_launch(void* const* d_in, const int* in_sizes, int n_in,
                              void* d_out, int out_size, void* d_ws, size_t ws_size,
                              hipStream_t stream) {
  (void)in_sizes; (void)n_in; (void)out_size; (void)ws_size;
  const float* x   = (const float*)d_in[0];
  const float* Wk  = (const float*)d_in[1];
  const float* bk  = (const float*)d_in[2];
  const float* Wv  = (const float*)d_in[3];
  const float* bv  = (const float*)d_in[4];
  const float* Wq  = (const float*)d_in[5];
  const float* bq  = (const float*)d_in[6];
  const float* Wkp = (const float*)d_in[7];
  const float* bkp = (const float*)d_in[8];
  const float* Wqp = (const float*)d_in[9];
  const float* bqp = (const float*)d_in[10];
  const float* ps  = (const float*)d_in[11];
  const float* lng = (const float*)d_in[12];
  const float* lnb = (const float*)d_in[13];
  const float* Wo  = (const float*)d_in[14];
  const float* bo  = (const float*)d_in[15];
  float* out = (float*)d_out;

  char* ws = (char*)d_ws;
  bf16*  KVQ  = (bf16*)(ws);                  // [16384,3072] bf16  100,663,296 B
  bf16*  T    = (bf16*)(ws + 100663296);      // [32768,1024] bf16   67,108,864 B
  bf16*  XB   = (bf16*)(ws + 167772160);      // [16384,1024] bf16 (xb, later ln out)
  bf16*  WKVQ = (bf16*)(ws + 201326592);      // [3072,1024] bf16
  bf16*  WP   = (bf16*)(ws + 207618048);      // [2048,1024] bf16 (Wkp;Wqp)
  bf16*  WOB  = (bf16*)(ws + 211812352);      // [1024,1024] bf16
  float* BKVQ = (float*)(ws + 213909504);     // [3072] f32
  float* BPP  = (float*)(ws + 213921792);     // [2048] f32

  // conversions
  f2b_kernel<<<16384, 256, 0, stream>>>(x, XB, 16777216L);
  f2b_kernel<<<1024, 256, 0, stream>>>(Wk, WKVQ, 1048576L);
  f2b_kernel<<<1024, 256, 0, stream>>>(Wv, WKVQ + 1048576, 1048576L);
  f2b_kernel<<<1024, 256, 0, stream>>>(Wq, WKVQ + 2097152, 1048576L);
  f2b_kernel<<<1024, 256, 0, stream>>>(Wkp, WP, 1048576L);
  f2b_kernel<<<1024, 256, 0, stream>>>(Wqp, WP + 1048576, 1048576L);
  f2b_kernel<<<1024, 256, 0, stream>>>(Wo, WOB, 1048576L);
  hipMemcpyAsync(BKVQ, bk, 4096, hipMemcpyDeviceToDevice, stream);
  hipMemcpyAsync(BKVQ + 1024, bv, 4096, hipMemcpyDeviceToDevice, stream);
  hipMemcpyAsync(BKVQ + 2048, bq, 4096, hipMemcpyDeviceToDevice, stream);
  hipMemcpyAsync(BPP, bkp, 4096, hipMemcpyDeviceToDevice, stream);
  hipMemcpyAsync(BPP + 1024, bqp, 4096, hipMemcpyDeviceToDevice, stream);

  // GEMM1: KVQ = XB @ [Wk;Wv;Wq]^T + [bk;bv;bq]   (M=16384, N=3072, K=1024)
  gemm_bt<0><<<dim3(24, 128), 256, 0, stream>>>(XB, 1024, WKVQ, 1024, BKVQ, KVQ, 3072, nullptr, 0);
  // GEMM2: T = tanh([K;Q] @ [Wkp;Wqp]^T + [bkp;bqp])   (M=32768, N=1024)
  gemm_bt<1><<<dim3(8, 256), 256, 0, stream>>>(KVQ, 3072, WP, 1024, BPP, T, 1024, nullptr, 16384);
  // chunk scan + retrieve + LayerNorm  -> XB (reused)
  scan_ln_kernel<<<256, 256, 0, stream>>>(KVQ, T, ps, lng, lnb, XB);
  // GEMM3: out = x + LN @ Wo^T + bo   (M=16384, N=1024)
  gemm_bt<2><<<dim3(8, 128), 256, 0, stream>>>(XB, 1024, WOB, 1024, bo, out, 1024, x, 0);
}

// Round 2
// 526.581 us; speedup vs baseline: 1.1121x; 1.1121x over previous
//
#include <hip/hip_runtime.h>
#include <hip/hip_bf16.h>

typedef __hip_bfloat16 bf16;
typedef __attribute__((ext_vector_type(8))) short short8;
typedef __attribute__((ext_vector_type(4))) float f32x4;

struct alignas(8) bh4 { bf16 x, y, z, w; };

static __device__ __forceinline__ float b2f(bf16 h) { return __bfloat162float(h); }

// ---------------- fp32 -> bf16 conversion (n multiple of 4) ----------------
__global__ __launch_bounds__(256) void f2b_kernel(const float* __restrict__ s,
                                                  bf16* __restrict__ d, long n) {
  long i = ((long)blockIdx.x * 256 + threadIdx.x) * 4;
  if (i >= n) return;
  float4 v = *(const float4*)(s + i);
  bh4 o;
  o.x = __float2bfloat16(v.x); o.y = __float2bfloat16(v.y);
  o.z = __float2bfloat16(v.z); o.w = __float2bfloat16(v.w);
  *(bh4*)(d + i) = o;
}

// ---------------- fp32 [1024,1024] -> transposed bf16 ----------------------
__global__ __launch_bounds__(256) void f2bT_kernel(const float* __restrict__ src,
                                                   bf16* __restrict__ dst) {
  __shared__ bf16 tile[64][68];
  const int t = threadIdx.x;
  const int tr = t >> 4;          // 0..15
  const int tc = (t & 15) * 4;    // 0..60
  const int r0 = blockIdx.y * 64, c0 = blockIdx.x * 64;
#pragma unroll
  for (int i = 0; i < 4; ++i) {
    float4 v = *(const float4*)(src + (long)(r0 + tr + i * 16) * 1024 + c0 + tc);
    tile[tr + i * 16][tc + 0] = __float2bfloat16(v.x);
    tile[tr + i * 16][tc + 1] = __float2bfloat16(v.y);
    tile[tr + i * 16][tc + 2] = __float2bfloat16(v.z);
    tile[tr + i * 16][tc + 3] = __float2bfloat16(v.w);
  }
  __syncthreads();
#pragma unroll
  for (int i = 0; i < 4; ++i) {
    const int c = tr + i * 16;
    bh4 o;
    o.x = tile[tc + 0][c]; o.y = tile[tc + 1][c];
    o.z = tile[tc + 2][c]; o.w = tile[tc + 3][c];
    *(bh4*)(dst + (long)(c0 + c) * 1024 + r0 + tc) = o;  // dst[C][R] = src[R][C]
  }
}

// ---------------- small copies / bias fold ---------------------------------
__global__ __launch_bounds__(256) void copyvec_kernel(const float* __restrict__ s,
                                                      float* __restrict__ d) {
  int i = blockIdx.x * 256 + threadIdx.x;
  d[i] = s[i];
}

// BBIG[1024+b] = dot(Wsel[e,:], bsel) + bpsel[e], b in [0,2048)
__global__ __launch_bounds__(256)
void biasdot_kernel(const float* __restrict__ Wkp, const float* __restrict__ bk,
                    const float* __restrict__ bkp, const float* __restrict__ Wqp,
                    const float* __restrict__ bq, const float* __restrict__ bqp,
                    float* __restrict__ BBIG) {
  const int b = blockIdx.x;
  const int half = b >> 10, e = b & 1023;
  const float* Wrow = (half ? Wqp : Wkp) + (long)e * 1024;
  const float* bsrc = half ? bq : bk;
  const int tid = threadIdx.x;
  float4 w = *(const float4*)(Wrow + tid * 4);
  float4 bb = *(const float4*)(bsrc + tid * 4);
  float p = w.x * bb.x + w.y * bb.y + w.z * bb.z + w.w * bb.w;
#pragma unroll
  for (int off = 32; off > 0; off >>= 1) p += __shfl_down(p, off, 64);
  __shared__ float rs[4];
  if ((tid & 63) == 0) rs[tid >> 6] = p;
  __syncthreads();
  if (tid == 0)
    BBIG[1024 + b] = rs[0] + rs[1] + rs[2] + rs[3] + (half ? bqp : bkp)[e];
}

// ---------------- bf16 GEMM, C[M,N] = A[M,K] @ W[N,K]^T (+ epilogue) -------
// MODE 0 (prep): no bias, bf16 out; rows >= 1024 switch W to second matrix.
// MODE 1 (main): bf16 out = acc + bias[col], tanh if col0 >= 1024.
// MODE 2 (final): f32 out = acc + bias[col] + resid[r*ldc+col].
// XCD swizzle: id&7 = XCD owns col-band of NXB tiles; row-tiles swept with
// col-fast inner order so the A-tile is L2-resident across its reuses.
#define TILE 128
#define BK 64

template <int MODE, int NXB>
__global__ __launch_bounds__(256)
void gemm_bt(const bf16* __restrict__ A, const bf16* __restrict__ W,
             const float* __restrict__ bias, void* __restrict__ Out,
             long lda, long ldc, int K,
             const float* __restrict__ resid) {
  __shared__ bf16 sA[TILE * BK];
  __shared__ bf16 sB[TILE * BK];

  const int id = blockIdx.x;
  const int xcd = id & 7;
  const int loc = id >> 3;
  const int bx = xcd * NXB + loc % NXB;
  const int by = loc / NXB;

  const int tid = threadIdx.x;
  const long row0 = (long)by * TILE;
  const long col0 = (long)bx * TILE;

  if (MODE == 0 && row0 >= 1024) W += 1024L * K;

  const int wave = tid >> 6;
  const int lane = tid & 63;
  const int wm = wave >> 1, wn = wave & 1;
  const int fr = lane & 15, quad = lane >> 4;

  f32x4 acc[4][4];
#pragma unroll
  for (int i = 0; i < 4; ++i)
#pragma unroll
    for (int j = 0; j < 4; ++j) acc[i][j] = (f32x4)0.0f;

  const int urow = tid >> 3;        // + r*32 per staging round
  const int ucol = (tid & 7) * 8;

  for (int k0 = 0; k0 < K; k0 += BK) {
#pragma unroll
    for (int r = 0; r < 4; ++r) {
      const int rr = r * 32 + urow;
      const bf16* ga = A + (row0 + rr) * lda + k0 + ucol;
      const bf16* gb = W + (col0 + rr) * (long)K + k0 + ucol;
      bf16* la = &sA[(r * 256 + (wave << 6)) * 8];
      bf16* lb = &sB[(r * 256 + (wave << 6)) * 8];
      __builtin_amdgcn_global_load_lds((const __attribute__((address_space(1))) void*)ga,
                                       (__attribute__((address_space(3))) void*)la, 16, 0, 0);
      __builtin_amdgcn_global_load_lds((const __attribute__((address_space(1))) void*)gb,
                                       (__attribute__((address_space(3))) void*)lb, 16, 0, 0);
    }
    __syncthreads();

#pragma unroll
    for (int kk = 0; kk < BK; kk += 32) {
      short8 af[4], bfv[4];
#pragma unroll
      for (int i = 0; i < 4; ++i)
        af[i] = *(const short8*)&sA[(wm * 64 + i * 16 + fr) * BK + kk + quad * 8];
#pragma unroll
      for (int j = 0; j < 4; ++j)
        bfv[j] = *(const short8*)&sB[(wn * 64 + j * 16 + fr) * BK + kk + quad * 8];
#pragma unroll
      for (int i = 0; i < 4; ++i)
#pragma unroll
        for (int j = 0; j < 4; ++j)
          acc[i][j] = __builtin_amdgcn_mfma_f32_16x16x32_bf16(af[i], bfv[j], acc[i][j], 0, 0, 0);
    }
    __syncthreads();
  }

  const bool do_tanh = (MODE == 1) && (col0 >= 1024);
  // C/D layout: col = lane&15, row = quad*4 + reg (m89/m91 verified)
#pragma unroll
  for (int i = 0; i < 4; ++i) {
    const long rb = row0 + wm * 64 + i * 16 + quad * 4;
#pragma unroll
    for (int j = 0; j < 4; ++j) {
      const int col = (int)col0 + wn * 64 + j * 16 + fr;
      const float bc = (MODE == 0) ? 0.0f : bias[col];
#pragma unroll
      for (int reg = 0; reg < 4; ++reg) {
        const long r = rb + reg;
        float v = acc[i][j][reg] + bc;
        if (MODE == 0) {
          ((bf16*)Out)[r * ldc + col] = __float2bfloat16(v);
        } else if (MODE == 1) {
          if (do_tanh) v = tanhf(v);
          ((bf16*)Out)[r * ldc + col] = __float2bfloat16(v);
        } else {
          ((float*)Out)[r * ldc + col] = v + resid[r * ldc + col];
        }
      }
    }
  }
}

// ---------------- chunk-64 cumsum + retrieve + LayerNorm -------------------
// One block per (b,chunk). Phase 1 (per 32-token half): serial cumsum +
// retrieve, ret cached in LDS (bf16), per-wave LN partials to private slots —
// NO barriers. One __syncthreads, then phase 2 normalizes + writes.
__global__ __launch_bounds__(256)
void scan_ln_kernel(const bf16* __restrict__ PHS,   // [16384,3072]: V | tanh_k | tanh_q
                    const float* __restrict__ phase_scale,
                    const float* __restrict__ ln_g,
                    const float* __restrict__ ln_b,
                    bf16* __restrict__ out) {
  __shared__ bf16 sret[32 * 1028];   // stride 1028 to spread banks in phase 2
  __shared__ float psum[32 * 4], psq[32 * 4];

  const int tid = threadIdx.x;
  const long t0 = (long)blockIdx.x * 64;
  const int d = tid * 4;
  const int wid = tid >> 6, lane = tid & 63;

  const float inv2pi = 0.15915494309189535f;
  float4 ps = *(const float4*)(phase_scale + d);
  float psr[4] = {ps.x * inv2pi, ps.y * inv2pi, ps.z * inv2pi, ps.w * inv2pi};

  float ar[4] = {0.f, 0.f, 0.f, 0.f}, ai[4] = {0.f, 0.f, 0.f, 0.f};

  const int p2s = tid >> 3;          // phase-2 token slot 0..31
  const int oct = tid & 7;           // phase-2 feature octant

  for (int h = 0; h < 2; ++h) {
    for (int sl = 0; sl < 32; ++sl) {
      const long t = t0 + h * 32 + sl;
      const bf16* row = PHS + t * 3072;
      bh4 v4  = *(const bh4*)(row + d);
      bh4 tk4 = *(const bh4*)(row + 1024 + d);
      bh4 tq4 = *(const bh4*)(row + 2048 + d);
      float vv[4] = {b2f(v4.x), b2f(v4.y), b2f(v4.z), b2f(v4.w)};
      float tk[4] = {b2f(tk4.x), b2f(tk4.y), b2f(tk4.z), b2f(tk4.w)};
      float tq[4] = {b2f(tq4.x), b2f(tq4.y), b2f(tq4.z), b2f(tq4.w)};
      float ret[4];
      float lsum = 0.f, lsq = 0.f;
#pragma unroll
      for (int j = 0; j < 4; ++j) {
        float rk = tk[j] * psr[j];   // revolutions
        float rq = tq[j] * psr[j];
        float ck = __builtin_amdgcn_cosf(rk);
        float sk = __builtin_amdgcn_sinf(rk);
        float cq = __builtin_amdgcn_cosf(rq);
        float sq = __builtin_amdgcn_sinf(rq);
        ar[j] += vv[j] * ck;
        ai[j] += vv[j] * sk;
        ret[j] = (ar[j] * cq + ai[j] * sq) * 0.03125f;  // / sqrt(1024)
        lsum += ret[j];
        lsq += ret[j] * ret[j];
      }
      bh4 o;
      o.x = __float2bfloat16(ret[0]); o.y = __float2bfloat16(ret[1]);
      o.z = __float2bfloat16(ret[2]); o.w = __float2bfloat16(ret[3]);
      *(bh4*)&sret[sl * 1028 + d] = o;
#pragma unroll
      for (int off = 32; off > 0; off >>= 1) {
        lsum += __shfl_down(lsum, off, 64);
        lsq  += __shfl_down(lsq, off, 64);
      }
      if (lane == 0) { psum[sl * 4 + wid] = lsum; psq[sl * 4 + wid] = lsq; }
    }
    __syncthreads();
    {
      const int sl = p2s;
      const long t = t0 + h * 32 + sl;
      float sum = psum[sl * 4] + psum[sl * 4 + 1] + psum[sl * 4 + 2] + psum[sl * 4 + 3];
      float sq2 = psq[sl * 4] + psq[sl * 4 + 1] + psq[sl * 4 + 2] + psq[sl * 4 + 3];
      float mu = sum * (1.0f / 1024.0f);
      float var = sq2 * (1.0f / 1024.0f) - mu * mu;
      float rstd = rsqrtf(var + 1e-5f);
#pragma unroll 4
      for (int i = 0; i < 32; ++i) {
        const int f = oct * 4 + i * 32;
        bh4 r4 = *(const bh4*)&sret[sl * 1028 + f];
        float4 g4 = *(const float4*)(ln_g + f);
        float4 b4 = *(const float4*)(ln_b + f);
        bh4 o;
        o.x = __float2bfloat16((b2f(r4.x) - mu) * rstd * g4.x + b4.x);
        o.y = __float2bfloat16((b2f(r4.y) - mu) * rstd * g4.y + b4.y);
        o.z = __float2bfloat16((b2f(r4.z) - mu) * rstd * g4.z + b4.z);
        o.w = __float2bfloat16((b2f(r4.w) - mu) * rstd * g4.w + b4.w);
        *(bh4*)(out + t * 1024 + f) = o;
      }
    }
    __syncthreads();
  }
}

// ---------------------------------------------------------------------------
extern "C" void kernel_launch(void* const* d_in, const int* in_sizes, int n_in,
                              void* d_out, int out_size, void* d_ws, size_t ws_size,
                              hipStream_t stream) {
  (void)in_sizes; (void)n_in; (void)out_size; (void)ws_size;
  const float* x   = (const float*)d_in[0];
  const float* Wk  = (const float*)d_in[1];
  const float* bk  = (const float*)d_in[2];
  const float* Wv  = (const float*)d_in[3];
  const float* bv  = (const float*)d_in[4];
  const float* Wq  = (const float*)d_in[5];
  const float* bq  = (const float*)d_in[6];
  const float* Wkp = (const float*)d_in[7];
  const float* bkp = (const float*)d_in[8];
  const float* Wqp = (const float*)d_in[9];
  const float* bqp = (const float*)d_in[10];
  const float* ps  = (const float*)d_in[11];
  const float* lng = (const float*)d_in[12];
  const float* lnb = (const float*)d_in[13];
  const float* Wo  = (const float*)d_in[14];
  const float* bo  = (const float*)d_in[15];
  float* out = (float*)d_out;

  char* ws = (char*)d_ws;
  bf16*  XB   = (bf16*)(ws);                  // [16384,1024] bf16 (x, later LN out)
  bf16*  PHS  = (bf16*)(ws + 33554432);       // [16384,3072] bf16: V | tanh_k | tanh_q
  bf16*  WBIG = (bf16*)(ws + 134217728);      // [3072,1024]: Wv | Wck | Wcq
  bf16*  WOB  = (bf16*)(ws + 140509184);      // [1024,1024]
  bf16*  WPS  = (bf16*)(ws + 142606336);      // [2048,1024]: Wkp ; Wqp (bf16)
  bf16*  WTS  = (bf16*)(ws + 146800640);      // [2048,1024]: Wk^T ; Wq^T (bf16)
  float* BBIG = (float*)(ws + 150994944);     // [3072]: bv | b'k | b'q

  // conversions / weight prep
  f2b_kernel<<<16384, 256, 0, stream>>>(x, XB, 16777216L);
  f2b_kernel<<<1024, 256, 0, stream>>>(Wv, WBIG, 1048576L);
  f2b_kernel<<<1024, 256, 0, stream>>>(Wkp, WPS, 1048576L);
  f2b_kernel<<<1024, 256, 0, stream>>>(Wqp, WPS + 1048576, 1048576L);
  f2b_kernel<<<1024, 256, 0, stream>>>(Wo, WOB, 1048576L);
  f2bT_kernel<<<dim3(16, 16), 256, 0, stream>>>(Wk, WTS);
  f2bT_kernel<<<dim3(16, 16), 256, 0, stream>>>(Wq, WTS + 1048576);
  copyvec_kernel<<<4, 256, 0, stream>>>(bv, BBIG);
  biasdot_kernel<<<2048, 256, 0, stream>>>(Wkp, bk, bkp, Wqp, bq, bqp, BBIG);

  // prep GEMM: [Wck;Wcq] = [Wkp;Wqp] @ [Wk^T;Wq^T]^T  (M=2048,N=1024,K=1024)
  gemm_bt<0, 1><<<128, 256, 0, stream>>>(WPS, WTS, nullptr, WBIG + 1048576,
                                         1024, 1024, 1024, nullptr);
  // main GEMM: PHS = [x@Wv^T+bv | tanh(x@Wck^T+b'k) | tanh(x@Wcq^T+b'q)]
  gemm_bt<1, 3><<<3072, 256, 0, stream>>>(XB, WBIG, BBIG, PHS,
                                          1024, 3072, 1024, nullptr);
  // chunk scan + retrieve + LayerNorm -> XB (reused)
  scan_ln_kernel<<<256, 256, 0, stream>>>(PHS, ps, lng, lnb, XB);
  // final GEMM: out = x + LN @ Wo^T + bo
  gemm_bt<2, 1><<<1024, 256, 0, stream>>>(XB, WOB, bo, out,
                                          1024, 1024, 1024, x);
}

// Round 3
// 450.099 us; speedup vs baseline: 1.3011x; 1.1699x over previous
//
#include <hip/hip_runtime.h>
#include <hip/hip_bf16.h>

typedef __hip_bfloat16 bf16;
typedef __attribute__((ext_vector_type(8))) short short8;
typedef __attribute__((ext_vector_type(4))) float f32x4;

struct alignas(8) bh4 { bf16 x, y, z, w; };

static __device__ __forceinline__ float b2f(bf16 h) { return __bfloat162float(h); }

// fast tanh: 1 - 2/(exp(2v)+1); saturates correctly via inf/0
static __device__ __forceinline__ float fast_tanh(float v) {
  float e = __expf(2.0f * v);
  return 1.0f - 2.0f * __builtin_amdgcn_rcpf(e + 1.0f);
}

// ---------------- fp32 -> bf16 conversion (x input) ------------------------
__global__ __launch_bounds__(256) void f2b_kernel(const float* __restrict__ s,
                                                  bf16* __restrict__ d, long n) {
  long i = ((long)blockIdx.x * 256 + threadIdx.x) * 4;
  if (i >= n) return;
  float4 v = *(const float4*)(s + i);
  bh4 o;
  o.x = __float2bfloat16(v.x); o.y = __float2bfloat16(v.y);
  o.z = __float2bfloat16(v.z); o.w = __float2bfloat16(v.w);
  *(bh4*)(d + i) = o;
}

// 4 x [1024,1024] fp32->bf16 in one launch
struct Ptrs4 { const float* s[4]; bf16* d[4]; };
__global__ __launch_bounds__(256) void f2b4_kernel(Ptrs4 p) {
  const int which = blockIdx.x >> 10;
  long i = ((long)(blockIdx.x & 1023) * 256 + threadIdx.x) * 4;
  float4 v = *(const float4*)(p.s[which] + i);
  bh4 o;
  o.x = __float2bfloat16(v.x); o.y = __float2bfloat16(v.y);
  o.z = __float2bfloat16(v.z); o.w = __float2bfloat16(v.w);
  *(bh4*)(p.d[which] + i) = o;
}

// ---------------- fp32 [1024,1024] -> transposed bf16 (2 mats) -------------
__global__ __launch_bounds__(256) void f2bT_kernel(const float* __restrict__ s0,
                                                   const float* __restrict__ s1,
                                                   bf16* __restrict__ d0,
                                                   bf16* __restrict__ d1) {
  const float* src = blockIdx.z ? s1 : s0;
  bf16* dst = blockIdx.z ? d1 : d0;
  __shared__ bf16 tile[64][68];
  const int t = threadIdx.x;
  const int tr = t >> 4;          // 0..15
  const int tc = (t & 15) * 4;    // 0..60
  const int r0 = blockIdx.y * 64, c0 = blockIdx.x * 64;
#pragma unroll
  for (int i = 0; i < 4; ++i) {
    float4 v = *(const float4*)(src + (long)(r0 + tr + i * 16) * 1024 + c0 + tc);
    tile[tr + i * 16][tc + 0] = __float2bfloat16(v.x);
    tile[tr + i * 16][tc + 1] = __float2bfloat16(v.y);
    tile[tr + i * 16][tc + 2] = __float2bfloat16(v.z);
    tile[tr + i * 16][tc + 3] = __float2bfloat16(v.w);
  }
  __syncthreads();
#pragma unroll
  for (int i = 0; i < 4; ++i) {
    const int c = tr + i * 16;
    bh4 o;
    o.x = tile[tc + 0][c]; o.y = tile[tc + 1][c];
    o.z = tile[tc + 2][c]; o.w = tile[tc + 3][c];
    *(bh4*)(dst + (long)(c0 + c) * 1024 + r0 + tc) = o;  // dst[C][R] = src[R][C]
  }
}

// ---------------- small copies / bias fold ---------------------------------
__global__ __launch_bounds__(256) void copyvec_kernel(const float* __restrict__ s,
                                                      float* __restrict__ d) {
  int i = blockIdx.x * 256 + threadIdx.x;
  d[i] = s[i];
}

// BBIG[1024+b] = dot(Wsel[e,:], bsel) + bpsel[e], b in [0,2048)
__global__ __launch_bounds__(256)
void biasdot_kernel(const float* __restrict__ Wkp, const float* __restrict__ bk,
                    const float* __restrict__ bkp, const float* __restrict__ Wqp,
                    const float* __restrict__ bq, const float* __restrict__ bqp,
                    float* __restrict__ BBIG) {
  const int b = blockIdx.x;
  const int half = b >> 10, e = b & 1023;
  const float* Wrow = (half ? Wqp : Wkp) + (long)e * 1024;
  const float* bsrc = half ? bq : bk;
  const int tid = threadIdx.x;
  float4 w = *(const float4*)(Wrow + tid * 4);
  float4 bb = *(const float4*)(bsrc + tid * 4);
  float p = w.x * bb.x + w.y * bb.y + w.z * bb.z + w.w * bb.w;
#pragma unroll
  for (int off = 32; off > 0; off >>= 1) p += __shfl_down(p, off, 64);
  __shared__ float rs[4];
  if ((tid & 63) == 0) rs[tid >> 6] = p;
  __syncthreads();
  if (tid == 0)
    BBIG[1024 + b] = rs[0] + rs[1] + rs[2] + rs[3] + (half ? bqp : bkp)[e];
}

// ---------------- bf16 GEMM, C[M,N] = A[M,K] @ W[N,K]^T (+ epilogue) -------
// MODE 0 (prep): no bias, bf16 out; rows >= 1024 switch W to second matrix.
// MODE 1 (main): bf16 out = acc + bias[col], fast_tanh if col0 >= 1024.
// MODE 2 (final): f32 out = acc + bias[col] + resid[r*ldc+col].
// LDS XOR swizzle: slot (row, g) holds global col-group g^(row&7) so that
// fragment ds_read_b128 lands 2-way-per-bank (free) instead of 16-way.
#define TILE 128
#define BK 64

template <int MODE, int NXB>
__global__ __launch_bounds__(256)
void gemm_bt(const bf16* __restrict__ A, const bf16* __restrict__ W,
             const float* __restrict__ bias, void* __restrict__ Out,
             long lda, long ldc, int K,
             const float* __restrict__ resid) {
  __shared__ bf16 sA[TILE * BK];
  __shared__ bf16 sB[TILE * BK];

  const int id = blockIdx.x;
  const int xcd = id & 7;
  const int loc = id >> 3;
  const int bx = xcd * NXB + loc % NXB;
  const int by = loc / NXB;

  const int tid = threadIdx.x;
  const long row0 = (long)by * TILE;
  const long col0 = (long)bx * TILE;

  if (MODE == 0 && row0 >= 1024) W += 1024L * K;

  const int wave = tid >> 6;
  const int lane = tid & 63;
  const int wm = wave >> 1, wn = wave & 1;
  const int fr = lane & 15, quad = lane >> 4;
  const int sw = fr & 7;            // read-side XOR swizzle key

  f32x4 acc[4][4];
#pragma unroll
  for (int i = 0; i < 4; ++i)
#pragma unroll
    for (int j = 0; j < 4; ++j) acc[i][j] = (f32x4)0.0f;

  const int urow = tid >> 3;                      // + r*32 per staging round
  const int gcolg = (tid & 7) ^ (urow & 7);       // swizzled global col group
  const int ucol = gcolg * 8;

  for (int k0 = 0; k0 < K; k0 += BK) {
#pragma unroll
    for (int r = 0; r < 4; ++r) {
      const int rr = r * 32 + urow;
      const bf16* ga = A + (row0 + rr) * lda + k0 + ucol;
      const bf16* gb = W + (col0 + rr) * (long)K + k0 + ucol;
      bf16* la = &sA[(r * 256 + (wave << 6)) * 8];
      bf16* lb = &sB[(r * 256 + (wave << 6)) * 8];
      __builtin_amdgcn_global_load_lds((const __attribute__((address_space(1))) void*)ga,
                                       (__attribute__((address_space(3))) void*)la, 16, 0, 0);
      __builtin_amdgcn_global_load_lds((const __attribute__((address_space(1))) void*)gb,
                                       (__attribute__((address_space(3))) void*)lb, 16, 0, 0);
    }
    __syncthreads();

#pragma unroll
    for (int kk = 0; kk < BK; kk += 32) {
      const int kg = kk >> 3;
      short8 af[4], bfv[4];
#pragma unroll
      for (int i = 0; i < 4; ++i)
        af[i] = *(const short8*)&sA[(wm * 64 + i * 16 + fr) * BK + (((kg + quad) ^ sw) << 3)];
#pragma unroll
      for (int j = 0; j < 4; ++j)
        bfv[j] = *(const short8*)&sB[(wn * 64 + j * 16 + fr) * BK + (((kg + quad) ^ sw) << 3)];
#pragma unroll
      for (int i = 0; i < 4; ++i)
#pragma unroll
        for (int j = 0; j < 4; ++j)
          acc[i][j] = __builtin_amdgcn_mfma_f32_16x16x32_bf16(af[i], bfv[j], acc[i][j], 0, 0, 0);
    }
    __syncthreads();
  }

  const bool do_tanh = (MODE == 1) && (col0 >= 1024);
  // C/D layout: col = lane&15, row = quad*4 + reg (m89/m91 verified)
#pragma unroll
  for (int i = 0; i < 4; ++i) {
    const long rb = row0 + wm * 64 + i * 16 + quad * 4;
#pragma unroll
    for (int j = 0; j < 4; ++j) {
      const int col = (int)col0 + wn * 64 + j * 16 + fr;
      const float bc = (MODE == 0) ? 0.0f : bias[col];
#pragma unroll
      for (int reg = 0; reg < 4; ++reg) {
        const long r = rb + reg;
        float v = acc[i][j][reg] + bc;
        if (MODE == 0) {
          ((bf16*)Out)[r * ldc + col] = __float2bfloat16(v);
        } else if (MODE == 1) {
          if (do_tanh) v = fast_tanh(v);
          ((bf16*)Out)[r * ldc + col] = __float2bfloat16(v);
        } else {
          ((float*)Out)[r * ldc + col] = v + resid[r * ldc + col];
        }
      }
    }
  }
}

// ---------------- chunk-64 cumsum + retrieve + LayerNorm -------------------
// One block per (b,chunk). Phase 1 (per 32-token half): serial cumsum +
// retrieve, ret cached in LDS (bf16), per-wave LN partials to private slots —
// NO barriers. One __syncthreads, then phase 2 normalizes + writes.
__global__ __launch_bounds__(256)
void scan_ln_kernel(const bf16* __restrict__ PHS,   // [16384,3072]: V | tanh_k | tanh_q
                    const float* __restrict__ phase_scale,
                    const float* __restrict__ ln_g,
                    const float* __restrict__ ln_b,
                    bf16* __restrict__ out) {
  __shared__ bf16 sret[32 * 1040];   // stride 1040: 2-way max in phase 2
  __shared__ float psum[32 * 4], psq[32 * 4];

  const int tid = threadIdx.x;
  const long t0 = (long)blockIdx.x * 64;
  const int d = tid * 4;
  const int wid = tid >> 6, lane = tid & 63;

  const float inv2pi = 0.15915494309189535f;
  float4 ps = *(const float4*)(phase_scale + d);
  float psr[4] = {ps.x * inv2pi, ps.y * inv2pi, ps.z * inv2pi, ps.w * inv2pi};

  float ar[4] = {0.f, 0.f, 0.f, 0.f}, ai[4] = {0.f, 0.f, 0.f, 0.f};

  const int p2s = tid >> 3;          // phase-2 token slot 0..31
  const int oct = tid & 7;           // phase-2 feature octant

  for (int h = 0; h < 2; ++h) {
    for (int sl = 0; sl < 32; ++sl) {
      const long t = t0 + h * 32 + sl;
      const bf16* row = PHS + t * 3072;
      bh4 v4  = *(const bh4*)(row + d);
      bh4 tk4 = *(const bh4*)(row + 1024 + d);
      bh4 tq4 = *(const bh4*)(row + 2048 + d);
      float vv[4] = {b2f(v4.x), b2f(v4.y), b2f(v4.z), b2f(v4.w)};
      float tk[4] = {b2f(tk4.x), b2f(tk4.y), b2f(tk4.z), b2f(tk4.w)};
      float tq[4] = {b2f(tq4.x), b2f(tq4.y), b2f(tq4.z), b2f(tq4.w)};
      float ret[4];
      float lsum = 0.f, lsq = 0.f;
#pragma unroll
      for (int j = 0; j < 4; ++j) {
        float rk = tk[j] * psr[j];   // revolutions
        float rq = tq[j] * psr[j];
        float ck = __builtin_amdgcn_cosf(rk);
        float sk = __builtin_amdgcn_sinf(rk);
        float cq = __builtin_amdgcn_cosf(rq);
        float sq = __builtin_amdgcn_sinf(rq);
        ar[j] += vv[j] * ck;
        ai[j] += vv[j] * sk;
        ret[j] = (ar[j] * cq + ai[j] * sq) * 0.03125f;  // / sqrt(1024)
        lsum += ret[j];
        lsq += ret[j] * ret[j];
      }
      bh4 o;
      o.x = __float2bfloat16(ret[0]); o.y = __float2bfloat16(ret[1]);
      o.z = __float2bfloat16(ret[2]); o.w = __float2bfloat16(ret[3]);
      *(bh4*)&sret[sl * 1040 + d] = o;
#pragma unroll
      for (int off = 32; off > 0; off >>= 1) {
        lsum += __shfl_down(lsum, off, 64);
        lsq  += __shfl_down(lsq, off, 64);
      }
      if (lane == 0) { psum[sl * 4 + wid] = lsum; psq[sl * 4 + wid] = lsq; }
    }
    __syncthreads();
    {
      const int sl = p2s;
      const long t = t0 + h * 32 + sl;
      float sum = psum[sl * 4] + psum[sl * 4 + 1] + psum[sl * 4 + 2] + psum[sl * 4 + 3];
      float sq2 = psq[sl * 4] + psq[sl * 4 + 1] + psq[sl * 4 + 2] + psq[sl * 4 + 3];
      float mu = sum * (1.0f / 1024.0f);
      float var = sq2 * (1.0f / 1024.0f) - mu * mu;
      float rstd = rsqrtf(var + 1e-5f);
#pragma unroll 4
      for (int i = 0; i < 32; ++i) {
        const int f = oct * 4 + i * 32;
        bh4 r4 = *(const bh4*)&sret[sl * 1040 + f];
        float4 g4 = *(const float4*)(ln_g + f);
        float4 b4 = *(const float4*)(ln_b + f);
        bh4 o;
        o.x = __float2bfloat16((b2f(r4.x) - mu) * rstd * g4.x + b4.x);
        o.y = __float2bfloat16((b2f(r4.y) - mu) * rstd * g4.y + b4.y);
        o.z = __float2bfloat16((b2f(r4.z) - mu) * rstd * g4.z + b4.z);
        o.w = __float2bfloat16((b2f(r4.w) - mu) * rstd * g4.w + b4.w);
        *(bh4*)(out + t * 1024 + f) = o;
      }
    }
    __syncthreads();
  }
}

// ---------------------------------------------------------------------------
extern "C" void kernel_launch(void* const* d_in, const int* in_sizes, int n_in,
                              void* d_out, int out_size, void* d_ws, size_t ws_size,
                              hipStream_t stream) {
  (void)in_sizes; (void)n_in; (void)out_size; (void)ws_size;
  const float* x   = (const float*)d_in[0];
  const float* Wk  = (const float*)d_in[1];
  const float* bk  = (const float*)d_in[2];
  const float* Wv  = (const float*)d_in[3];
  const float* bv  = (const float*)d_in[4];
  const float* Wq  = (const float*)d_in[5];
  const float* bq  = (const float*)d_in[6];
  const float* Wkp = (const float*)d_in[7];
  const float* bkp = (const float*)d_in[8];
  const float* Wqp = (const float*)d_in[9];
  const float* bqp = (const float*)d_in[10];
  const float* ps  = (const float*)d_in[11];
  const float* lng = (const float*)d_in[12];
  const float* lnb = (const float*)d_in[13];
  const float* Wo  = (const float*)d_in[14];
  const float* bo  = (const float*)d_in[15];
  float* out = (float*)d_out;

  char* ws = (char*)d_ws;
  bf16*  XB   = (bf16*)(ws);                  // [16384,1024] bf16 (x, later LN out)
  bf16*  PHS  = (bf16*)(ws + 33554432);       // [16384,3072] bf16: V | tanh_k | tanh_q
  bf16*  WBIG = (bf16*)(ws + 134217728);      // [3072,1024]: Wv | Wck | Wcq
  bf16*  WOB  = (bf16*)(ws + 140509184);      // [1024,1024]
  bf16*  WPS  = (bf16*)(ws + 142606336);      // [2048,1024]: Wkp ; Wqp (bf16)
  bf16*  WTS  = (bf16*)(ws + 146800640);      // [2048,1024]: Wk^T ; Wq^T (bf16)
  float* BBIG = (float*)(ws + 150994944);     // [3072]: bv | b'k | b'q

  // conversions / weight prep
  f2b_kernel<<<16384, 256, 0, stream>>>(x, XB, 16777216L);
  Ptrs4 p4;
  p4.s[0] = Wv;  p4.d[0] = WBIG;
  p4.s[1] = Wkp; p4.d[1] = WPS;
  p4.s[2] = Wqp; p4.d[2] = WPS + 1048576;
  p4.s[3] = Wo;  p4.d[3] = WOB;
  f2b4_kernel<<<4096, 256, 0, stream>>>(p4);
  f2bT_kernel<<<dim3(16, 16, 2), 256, 0, stream>>>(Wk, Wq, WTS, WTS + 1048576);
  copyvec_kernel<<<4, 256, 0, stream>>>(bv, BBIG);
  biasdot_kernel<<<2048, 256, 0, stream>>>(Wkp, bk, bkp, Wqp, bq, bqp, BBIG);

  // prep GEMM: [Wck;Wcq] = [Wkp;Wqp] @ [Wk^T;Wq^T]^T  (M=2048,N=1024,K=1024)
  gemm_bt<0, 1><<<128, 256, 0, stream>>>(WPS, WTS, nullptr, WBIG + 1048576,
                                         1024, 1024, 1024, nullptr);
  // main GEMM: PHS = [x@Wv^T+bv | tanh(x@Wck^T+b'k) | tanh(x@Wcq^T+b'q)]
  gemm_bt<1, 3><<<3072, 256, 0, stream>>>(XB, WBIG, BBIG, PHS,
                                          1024, 3072, 1024, nullptr);
  // chunk scan + retrieve + LayerNorm -> XB (reused)
  scan_ln_kernel<<<256, 256, 0, stream>>>(PHS, ps, lng, lnb, XB);
  // final GEMM: out = x + LN @ Wo^T + bo
  gemm_bt<2, 1><<<1024, 256, 0, stream>>>(XB, WOB, bo, out,
                                          1024, 1024, 1024, x);
}